// Round 20
// baseline (180.260 us; speedup 1.0000x reference)
//
#include <hip/hip_runtime.h>
#include <hip/hip_bf16.h>

// B=4, T=2048, C=1024, H=16, D=64. f32 in/out; bf16 MFMA internally.
// R20 = R19 GEMMs + attn reshaped to 4-wave/128-row blocks (grid 1024) with
// XCD-affinity (all 16 q-tiles of a bh on one XCD -> KV re-reads are L2 hits)
// and per-CU-slot complementary sizing (quadruple tile sum = 68, uniform).

typedef __attribute__((ext_vector_type(8))) short bf16x8;
typedef __attribute__((ext_vector_type(4))) float f32x4;
typedef __attribute__((ext_vector_type(16))) float f32x16;

#define T_DIM 2048
#define NHEAD 16
#define HDIM  64

__device__ __forceinline__ unsigned short f2bf(float f) {
    union { float f; unsigned int u; } v; v.f = f;
    unsigned int r = v.u + 0x7fffu + ((v.u >> 16) & 1u);   // RNE
    return (unsigned short)(r >> 16);
}

__device__ __forceinline__ unsigned cvtpk_bf16(float lo, float hi) {
    unsigned r;
    asm("v_cvt_pk_bf16_f32 %0, %1, %2" : "=v"(r) : "v"(lo), "v"(hi));
    return r;
}
__device__ __forceinline__ void pl32swap(unsigned &x, unsigned &y) {
    asm("v_permlane32_swap_b32 %0, %1" : "+v"(x), "+v"(y));
}
__device__ __forceinline__ bf16x8 mk8(unsigned w0, unsigned w1, unsigned w2, unsigned w3) {
    union { unsigned u[4]; bf16x8 v; } p;
    p.u[0] = w0; p.u[1] = w1; p.u[2] = w2; p.u[3] = w3;
    return p.v;
}

__device__ __forceinline__ void gload_lds16(const void* g, void* l) {
    __builtin_amdgcn_global_load_lds(
        (const __attribute__((address_space(1))) void*)g,
        (__attribute__((address_space(3))) void*)l,
        16, 0, 0);
}

// ---------------- f32 -> bf16 convert (vectorized) ----------------
__global__ void cvt_bf16_k(const float* __restrict__ src, unsigned short* __restrict__ dst, int n) {
    int i = (blockIdx.x * blockDim.x + threadIdx.x) * 4;
    if (i < n) {
        float4 v = *(const float4*)(src + i);
        ushort4 o; o.x = f2bf(v.x); o.y = f2bf(v.y); o.z = f2bf(v.z); o.w = f2bf(v.w);
        *(ushort4*)(dst + i) = o;
    }
}

// ---------------- transpose f32 [R][Cc] -> bf16 [Cc][R] ----------------
__global__ void transpose_wb_k(const float* __restrict__ src, unsigned short* __restrict__ dst,
                               int R, int Cc) {
    __shared__ float tile[32][33];
    int c0 = blockIdx.x * 32, r0 = blockIdx.y * 32;
    int tx = threadIdx.x & 31, ty = threadIdx.x >> 5;   // 32 x 8
    #pragma unroll
    for (int i = 0; i < 32; i += 8)
        tile[ty + i][tx] = src[(size_t)(r0 + ty + i) * Cc + c0 + tx];
    __syncthreads();
    #pragma unroll
    for (int i = 0; i < 32; i += 8)
        dst[(size_t)(c0 + ty + i) * R + r0 + tx] = f2bf(tile[tx][ty + i]);
}

// ---------------- 128x128 m97-structure GEMM (conflict-free XOR LDS), C = A * Bt^T ----------
// 4 waves (2M x 2N), per-wave 64x64 out. BK=64. Static LDS 32 KiB single-buffer:
// STAGE(t) -> sync -> 16 ds_read_b128 + 32 MFMA (setprio) -> sync.  ~3 blocks/CU.
// LDS [row][8ch][8], chunk XOR (row&7): staging = 8 rows x 128B contiguous per wave-load;
// readback kc=(ks*4+hi)^(lrow&7) -> 2-way max (free).
// EPI==0: Q 32B-run scatter (exp2-domain scale); K/V LDS-staged chunk-major. EPI==1: f32 [M,N].
template<int EPI>
__global__ __launch_bounds__(256) void gemm_bt_k(
    const unsigned short* __restrict__ A, const unsigned short* __restrict__ Bt,
    void* __restrict__ out0, void* __restrict__ out1, void* __restrict__ out2,
    int M, int N, int K)
{
    __shared__ __align__(16) unsigned short smem[16384];
    unsigned short* sA = smem;            // [128][8ch][8] = 8192 shorts
    unsigned short* sB = smem + 8192;

    const int tid = threadIdx.x, lane = tid & 63, wave = tid >> 6;
    const int wm = wave >> 1, wn = wave & 1;     // 2M x 2N
    const int lrow = lane & 15, hi = lane >> 4;

    // bijective XCD-chunked swizzle (nwg % 8 == 0)
    const int nwg = gridDim.x * gridDim.y;
    const int lin = blockIdx.y * gridDim.x + blockIdx.x;
    const int lin2 = (lin & 7) * (nwg >> 3) + (lin >> 3);
    const int bxg = lin2 % gridDim.x, byg = lin2 / gridDim.x;
    const int row0 = byg * 128, col0 = bxg * 128;

    const int arow = tid >> 3;
    const int gk = ((tid & 7) ^ (arow & 7)) * 8;
    const unsigned short* gA = A  + (size_t)(row0 + arow) * K + gk;
    const unsigned short* gB = Bt + (size_t)(col0 + arow) * K + gk;

    const int NT = K >> 6;

#define STAGE(t) { const size_t ko_ = (size_t)(t) * 64; \
        gload_lds16(gA + ko_,                   sA + tid * 8); \
        gload_lds16(gA + (size_t)32 * K + ko_,  sA + (tid + 256) * 8); \
        gload_lds16(gA + (size_t)64 * K + ko_,  sA + (tid + 512) * 8); \
        gload_lds16(gA + (size_t)96 * K + ko_,  sA + (tid + 768) * 8); \
        gload_lds16(gB + ko_,                   sB + tid * 8); \
        gload_lds16(gB + (size_t)32 * K + ko_,  sB + (tid + 256) * 8); \
        gload_lds16(gB + (size_t)64 * K + ko_,  sB + (tid + 512) * 8); \
        gload_lds16(gB + (size_t)96 * K + ko_,  sB + (tid + 768) * 8); }

    f32x4 acc[4][4] = {};

    for (int t = 0; t < NT; ++t) {
        STAGE(t);
        __syncthreads();   // drain: tile resident
        bf16x8 af[2][4], bf_[2][4];
        #pragma unroll
        for (int ks = 0; ks < 2; ++ks) {
            const int kc = (ks * 4 + hi) ^ (lrow & 7);
            #pragma unroll
            for (int mi = 0; mi < 4; ++mi)
                af[ks][mi] = *(const bf16x8*)&sA[((wm * 64 + mi * 16 + lrow) * 8 + kc) * 8];
            #pragma unroll
            for (int ni = 0; ni < 4; ++ni)
                bf_[ks][ni] = *(const bf16x8*)&sB[((wn * 64 + ni * 16 + lrow) * 8 + kc) * 8];
        }
        __builtin_amdgcn_s_setprio(1);
        #pragma unroll
        for (int ks = 0; ks < 2; ++ks)
            #pragma unroll
            for (int mi = 0; mi < 4; ++mi)
                #pragma unroll
                for (int ni = 0; ni < 4; ++ni)
                    acc[mi][ni] = __builtin_amdgcn_mfma_f32_16x16x32_bf16(af[ks][mi], bf_[ks][ni], acc[mi][ni], 0, 0, 0);
        __builtin_amdgcn_s_setprio(0);
        __syncthreads();   // all reads done before next overwrite
    }
#undef STAGE

    // epilogue: C/D layout row=hi*4+reg, col=lrow (verified m89)
    if (EPI == 1) {
        #pragma unroll
        for (int mi = 0; mi < 4; ++mi)
            #pragma unroll
            for (int ni = 0; ni < 4; ++ni) {
                int gm0 = row0 + wm * 64 + mi * 16 + hi * 4;
                int gn  = col0 + wn * 64 + ni * 16 + lrow;
                #pragma unroll
                for (int r = 0; r < 4; ++r)
                    ((float*)out0)[(size_t)(gm0 + r) * N + gn] = acc[mi][ni][r];
            }
    } else if (col0 < 1024) {
        // Q: natural [bh][t][d], exp2-domain scale; 32B-run scatter
        const int bb = row0 >> 11;
        #pragma unroll
        for (int mi = 0; mi < 4; ++mi)
            #pragma unroll
            for (int ni = 0; ni < 4; ++ni) {
                int gm0 = row0 + wm * 64 + mi * 16 + hi * 4;
                int gn  = col0 + wn * 64 + ni * 16 + lrow;
                int h = (gn >> 6) & 15, d = gn & 63;
                #pragma unroll
                for (int r = 0; r < 4; ++r) {
                    int t = (gm0 + r) & 2047;
                    ((unsigned short*)out0)[((size_t)(bb * NHEAD + h) * T_DIM + t) * HDIM + d] =
                        f2bf(acc[mi][ni][r] * 0.18033688011112042f);
                }
            }
    } else {
        // K/V: LDS-staged chunk-major -> fully coalesced global writes.
        const bool isK = (col0 < 2048);
        __syncthreads();   // staging LDS dead; safe to reuse
        #pragma unroll
        for (int mi = 0; mi < 4; ++mi) {
            #pragma unroll
            for (int ni = 0; ni < 4; ++ni) {
                const int gnl = wn * 64 + ni * 16 + lrow;   // 0..127 within block
                const int hl = gnl >> 6, d = gnl & 63;
                #pragma unroll
                for (int r = 0; r < 4; ++r) {
                    const int tl = wm * 64 + mi * 16 + hi * 4 + r;   // 0..127
                    int idx;
                    if (isK) idx = (hl * 2 + (tl >> 6)) * 4096 + ((d >> 3) * 64 + (tl & 63)) * 8 + (d & 7);
                    else     idx = (hl * 2 + (tl >> 6)) * 4096 + (((tl >> 3) & 7) * 64 + d) * 8 + (tl & 7);
                    smem[idx] = f2bf(acc[mi][ni][r]);
                }
            }
        }
        __syncthreads();
        unsigned short* outb = (unsigned short*)(isK ? out1 : out2);
        const int bb = row0 >> 11;
        const int h0 = ((col0 - (isK ? 1024 : 2048)) >> 6);   // 2-head aligned
        const int tc0 = (row0 & 2047) >> 6;
        #pragma unroll
        for (int seg = 0; seg < 4; ++seg) {
            const int hl = seg >> 1, tc = seg & 1;
            const size_t gbase = ((size_t)(bb * NHEAD + h0 + hl) * 32 + tc0 + tc) * 4096;
            *(uint4*)(outb + gbase + tid * 8)         = *(const uint4*)(smem + seg * 4096 + tid * 8);
            *(uint4*)(outb + gbase + (tid + 256) * 8) = *(const uint4*)(smem + seg * 4096 + (tid + 256) * 8);
        }
    }
}

// ---------------- causal flash attention: 4 waves x 32 q-rows, XCD-affinity ----------------
// grid 1024, 256 threads. Mapping: xcd=L&7, k=L>>3, c=k&31, j=k>>5;
//   bh = ((c>>4)*4 + j)*8 + xcd   (all 16 q-tiles of one bh on ONE XCD -> KV L2-resident)
//   bx = (j&1) ? 15-(c&15) : (c&15)  (4 blocks/CU-slot: tile sums 2*(s+15-s)+8 = 68, uniform)
// Bijective: (c>>4, j, c&15) <-> (bh_local, bx). 4 independent barrier domains per CU.
// S^T = mfma_32x32x16(K, Q); P = exp2(S-16) in regs; cvt_pk + permlane32_swap; no P LDS.
__global__ __launch_bounds__(256) void attn_k(
    const unsigned short* __restrict__ qb, const unsigned short* __restrict__ kcm,
    const unsigned short* __restrict__ vcm, unsigned short* __restrict__ yb)
{
    __shared__ __align__(16) unsigned short Ks[2][4096];
    __shared__ __align__(16) unsigned short Vs[2][4096];

    const int tid = threadIdx.x, lane = tid & 63, wave = tid >> 6;
    const int L = (int)blockIdx.x;
    const int k = L >> 3;
    const int c = k & 31, j = k >> 5;
    const int bh = (((c >> 4) << 2) | j) * 8 + (L & 7);
    const int bx = (j & 1) ? 15 - (c & 15) : (c & 15);

    const int q32 = lane & 31, hi32 = lane >> 5;
    const unsigned short* Kg = kcm + (size_t)bh * 32 * 4096;
    const unsigned short* Vg = vcm + (size_t)bh * 32 * 4096;

    const int ntiles = 2 * bx + 2;
    const int q0w = bx * 128 + wave * 32;
    const int qg = q0w + q32;

    // Q B-fragments direct from global (pre-scaled into exp2 domain)
    const unsigned short* qrow = qb + ((size_t)bh * T_DIM + q0w + q32) * HDIM;
    bf16x8 qf[4];
    #pragma unroll
    for (int kc = 0; kc < 4; ++kc)
        qf[kc] = *(const bf16x8*)(qrow + kc * 16 + hi32 * 8);

    f32x16 o0 = {}, o1 = {};
    float lsum = 0.f;

    gload_lds16(Kg + tid * 8, &Ks[0][tid * 8]);
    gload_lds16(Kg + (tid + 256) * 8, &Ks[0][(tid + 256) * 8]);
    gload_lds16(Vg + tid * 8, &Vs[0][tid * 8]);
    gload_lds16(Vg + (tid + 256) * 8, &Vs[0][(tid + 256) * 8]);
    __syncthreads();

    int cur = 0;
    for (int jt = 0; jt < ntiles; ++jt) {
        if (jt + 1 < ntiles) {
            const size_t nb = (size_t)(jt + 1) * 4096;
            gload_lds16(Kg + nb + tid * 8, &Ks[cur ^ 1][tid * 8]);
            gload_lds16(Kg + nb + (tid + 256) * 8, &Ks[cur ^ 1][(tid + 256) * 8]);
            gload_lds16(Vg + nb + tid * 8, &Vs[cur ^ 1][tid * 8]);
            gload_lds16(Vg + nb + (tid + 256) * 8, &Vs[cur ^ 1][(tid + 256) * 8]);
        }
        if (jt * 64 <= q0w + 31) {   // wave-uniform skip of fully-masked tiles
            // S^T = K · Q  (exp2 domain)
            f32x16 s0 = {}, s1 = {};
            #pragma unroll
            for (int kc = 0; kc < 4; ++kc) {
                bf16x8 a0 = *(const bf16x8*)&Ks[cur][((kc * 2 + hi32) * 64 + q32) * 8];
                bf16x8 a1 = *(const bf16x8*)&Ks[cur][((kc * 2 + hi32) * 64 + 32 + q32) * 8];
                s0 = __builtin_amdgcn_mfma_f32_32x32x16_bf16(a0, qf[kc], s0, 0, 0, 0);
                s1 = __builtin_amdgcn_mfma_f32_32x32x16_bf16(a1, qf[kc], s1, 0, 0, 0);
            }
            // causal mask (diagonal tiles only); kv = jt*64 + blk*32 + crow(r)
            if (jt * 64 + 63 > q0w) {
                #pragma unroll
                for (int r = 0; r < 16; ++r) {
                    int kv0 = jt * 64 + (r & 3) + 8 * (r >> 2) + 4 * hi32;
                    if (kv0 > qg)      s0[r] = -1e30f;
                    if (kv0 + 32 > qg) s1[r] = -1e30f;
                }
            }
            // P = exp2(S-16); pack to bf16; permlane-assemble PV A-frags
            bf16x8 pa[4];
            #pragma unroll
            for (int blk = 0; blk < 2; ++blk) {
                float p_[16]; unsigned w_[8];
                #pragma unroll
                for (int i = 0; i < 16; ++i) {
                    float sv = blk ? s1[i] : s0[i];
                    p_[i] = __builtin_amdgcn_exp2f(sv - 16.0f);
                    lsum += p_[i];
                }
                #pragma unroll
                for (int i = 0; i < 8; ++i) w_[i] = cvtpk_bf16(p_[2 * i], p_[2 * i + 1]);
                pl32swap(w_[0], w_[2]); pl32swap(w_[1], w_[3]);
                pl32swap(w_[4], w_[6]); pl32swap(w_[5], w_[7]);
                pa[blk * 2]     = mk8(w_[0], w_[1], w_[2], w_[3]);
                pa[blk * 2 + 1] = mk8(w_[4], w_[5], w_[6], w_[7]);
            }
            // O += P V
            #pragma unroll
            for (int kvc = 0; kvc < 4; ++kvc) {
                bf16x8 b0 = *(const bf16x8*)&Vs[cur][((kvc * 2 + hi32) * 64 + q32) * 8];
                bf16x8 b1 = *(const bf16x8*)&Vs[cur][((kvc * 2 + hi32) * 64 + 32 + q32) * 8];
                o0 = __builtin_amdgcn_mfma_f32_32x32x16_bf16(pa[kvc], b0, o0, 0, 0, 0);
                o1 = __builtin_amdgcn_mfma_f32_32x32x16_bf16(pa[kvc], b1, o1, 0, 0, 0);
            }
        }
        __syncthreads();   // drains prefetch; next tile ready
        cur ^= 1;
    }

    // l: own-half sum + partner-half via permlane pair
    {
        unsigned la = __float_as_uint(lsum), lb = __float_as_uint(lsum);
        pl32swap(la, lb);
        lsum = __uint_as_float(la) + __uint_as_float(lb);
    }
    // epilogue: y[b*T + t][h*64 + d]; l gathered per output row via shfl
    const int bb2 = bh >> 4, h = bh & 15;
    #pragma unroll
    for (int r = 0; r < 16; ++r) {
        const int cr = (r & 3) + 8 * (r >> 2) + 4 * hi32;
        float inv = 1.0f / __shfl(lsum, cr);
        int t = q0w + cr;
        size_t off = ((size_t)(bb2 * T_DIM + t)) * 1024 + h * HDIM + q32;
        yb[off]      = f2bf(o0[r] * inv);
        yb[off + 32] = f2bf(o1[r] * inv);
    }
}

extern "C" void kernel_launch(void* const* d_in, const int* in_sizes, int n_in,
                              void* d_out, int out_size, void* d_ws, size_t ws_size,
                              hipStream_t stream) {
    const float* x      = (const float*)d_in[0];   // [4,2048,1024]
    const float* w_attn = (const float*)d_in[1];   // [1024,3072]
    const float* w_proj = (const float*)d_in[2];   // [1024,1024]
    float* out = (float*)d_out;                    // [4,2048,1024]

    unsigned short* xb  = (unsigned short*)d_ws;           // [8192][1024]
    unsigned short* wat = xb  + (size_t)8192 * 1024;       // [3072][1024]
    unsigned short* wpt = wat + (size_t)3072 * 1024;       // [1024][1024]
    unsigned short* qb  = wpt + (size_t)1024 * 1024;       // [64][2048][64] natural
    unsigned short* kcm = qb  + (size_t)64 * 2048 * 64;    // [64][32][512][8] chunk-major
    unsigned short* vcm = kcm + (size_t)64 * 2048 * 64;    // [64][32][512][8] chunk-major-T
    unsigned short* yb  = vcm + (size_t)64 * 2048 * 64;    // [8192][1024]

    cvt_bf16_k<<<8192, 256, 0, stream>>>(x, xb, 8192 * 1024);
    transpose_wb_k<<<dim3(96, 32), 256, 0, stream>>>(w_attn, wat, 1024, 3072);
    transpose_wb_k<<<dim3(32, 32), 256, 0, stream>>>(w_proj, wpt, 1024, 1024);

    gemm_bt_k<0><<<dim3(24, 64), 256, 0, stream>>>(xb, wat, qb, kcm, vcm, 8192, 3072, 1024);
    attn_k<<<1024, 256, 0, stream>>>(qb, kcm, vcm, yb);
    gemm_bt_k<1><<<dim3(8, 64), 256, 0, stream>>>(yb, wpt, out, nullptr, nullptr, 8192, 1024, 1024);
}

// Round 21
// 162.201 us; speedup vs baseline: 1.1113x; 1.1113x over previous
//
#include <hip/hip_runtime.h>
#include <hip/hip_bf16.h>

// B=4, T=2048, C=1024, H=16, D=64. f32 in/out; bf16 MFMA internally.
// FINAL: exact R16/R19 configuration (best measured: 162.6 / 162.7 us).
// Explored and rejected: deep-pipeline GEMMs (R5/R6/R10/R11: all slower than the
// m97-structure + conflict-free XOR LDS), attn variants (4-wave paired R13, LDS-free
// R15, kv-split R18, 1024-block affinity R20: all regressed — dispatch placement is
// uncontrollable from HIP; 8-wave/256-row + XCD-affinity is the empirical optimum).

typedef __attribute__((ext_vector_type(8))) short bf16x8;
typedef __attribute__((ext_vector_type(4))) float f32x4;
typedef __attribute__((ext_vector_type(16))) float f32x16;

#define T_DIM 2048
#define NHEAD 16
#define HDIM  64

__device__ __forceinline__ unsigned short f2bf(float f) {
    union { float f; unsigned int u; } v; v.f = f;
    unsigned int r = v.u + 0x7fffu + ((v.u >> 16) & 1u);   // RNE
    return (unsigned short)(r >> 16);
}

__device__ __forceinline__ unsigned cvtpk_bf16(float lo, float hi) {
    unsigned r;
    asm("v_cvt_pk_bf16_f32 %0, %1, %2" : "=v"(r) : "v"(lo), "v"(hi));
    return r;
}
__device__ __forceinline__ void pl32swap(unsigned &x, unsigned &y) {
    asm("v_permlane32_swap_b32 %0, %1" : "+v"(x), "+v"(y));
}
__device__ __forceinline__ bf16x8 mk8(unsigned w0, unsigned w1, unsigned w2, unsigned w3) {
    union { unsigned u[4]; bf16x8 v; } p;
    p.u[0] = w0; p.u[1] = w1; p.u[2] = w2; p.u[3] = w3;
    return p.v;
}

__device__ __forceinline__ void gload_lds16(const void* g, void* l) {
    __builtin_amdgcn_global_load_lds(
        (const __attribute__((address_space(1))) void*)g,
        (__attribute__((address_space(3))) void*)l,
        16, 0, 0);
}

// ---------------- f32 -> bf16 convert (vectorized) ----------------
__global__ void cvt_bf16_k(const float* __restrict__ src, unsigned short* __restrict__ dst, int n) {
    int i = (blockIdx.x * blockDim.x + threadIdx.x) * 4;
    if (i < n) {
        float4 v = *(const float4*)(src + i);
        ushort4 o; o.x = f2bf(v.x); o.y = f2bf(v.y); o.z = f2bf(v.z); o.w = f2bf(v.w);
        *(ushort4*)(dst + i) = o;
    }
}

// ---------------- transpose f32 [R][Cc] -> bf16 [Cc][R] ----------------
__global__ void transpose_wb_k(const float* __restrict__ src, unsigned short* __restrict__ dst,
                               int R, int Cc) {
    __shared__ float tile[32][33];
    int c0 = blockIdx.x * 32, r0 = blockIdx.y * 32;
    int tx = threadIdx.x & 31, ty = threadIdx.x >> 5;   // 32 x 8
    #pragma unroll
    for (int i = 0; i < 32; i += 8)
        tile[ty + i][tx] = src[(size_t)(r0 + ty + i) * Cc + c0 + tx];
    __syncthreads();
    #pragma unroll
    for (int i = 0; i < 32; i += 8)
        dst[(size_t)(c0 + ty + i) * R + r0 + tx] = f2bf(tile[tx][ty + i]);
}

// ---------------- 128x128 m97-structure GEMM (conflict-free XOR LDS), C = A * Bt^T ----------
// 4 waves (2M x 2N), per-wave 64x64 out. BK=64. Static LDS 32 KiB single-buffer:
// STAGE(t) -> sync -> 16 ds_read_b128 + 32 MFMA (setprio) -> sync.  ~3 blocks/CU.
// LDS [row][8ch][8], chunk XOR (row&7): staging = 8 rows x 128B contiguous per wave-load;
// readback kc=(ks*4+hi)^(lrow&7) -> 2-way max (free).
// EPI==0: Q 32B-run scatter (exp2-domain scale); K/V LDS-staged chunk-major. EPI==1: f32 [M,N].
template<int EPI>
__global__ __launch_bounds__(256) void gemm_bt_k(
    const unsigned short* __restrict__ A, const unsigned short* __restrict__ Bt,
    void* __restrict__ out0, void* __restrict__ out1, void* __restrict__ out2,
    int M, int N, int K)
{
    __shared__ __align__(16) unsigned short smem[16384];
    unsigned short* sA = smem;            // [128][8ch][8] = 8192 shorts
    unsigned short* sB = smem + 8192;

    const int tid = threadIdx.x, lane = tid & 63, wave = tid >> 6;
    const int wm = wave >> 1, wn = wave & 1;     // 2M x 2N
    const int lrow = lane & 15, hi = lane >> 4;

    // bijective XCD-chunked swizzle (nwg % 8 == 0)
    const int nwg = gridDim.x * gridDim.y;
    const int lin = blockIdx.y * gridDim.x + blockIdx.x;
    const int lin2 = (lin & 7) * (nwg >> 3) + (lin >> 3);
    const int bxg = lin2 % gridDim.x, byg = lin2 / gridDim.x;
    const int row0 = byg * 128, col0 = bxg * 128;

    const int arow = tid >> 3;
    const int gk = ((tid & 7) ^ (arow & 7)) * 8;
    const unsigned short* gA = A  + (size_t)(row0 + arow) * K + gk;
    const unsigned short* gB = Bt + (size_t)(col0 + arow) * K + gk;

    const int NT = K >> 6;

#define STAGE(t) { const size_t ko_ = (size_t)(t) * 64; \
        gload_lds16(gA + ko_,                   sA + tid * 8); \
        gload_lds16(gA + (size_t)32 * K + ko_,  sA + (tid + 256) * 8); \
        gload_lds16(gA + (size_t)64 * K + ko_,  sA + (tid + 512) * 8); \
        gload_lds16(gA + (size_t)96 * K + ko_,  sA + (tid + 768) * 8); \
        gload_lds16(gB + ko_,                   sB + tid * 8); \
        gload_lds16(gB + (size_t)32 * K + ko_,  sB + (tid + 256) * 8); \
        gload_lds16(gB + (size_t)64 * K + ko_,  sB + (tid + 512) * 8); \
        gload_lds16(gB + (size_t)96 * K + ko_,  sB + (tid + 768) * 8); }

    f32x4 acc[4][4] = {};

    for (int t = 0; t < NT; ++t) {
        STAGE(t);
        __syncthreads();   // drain: tile resident
        bf16x8 af[2][4], bf_[2][4];
        #pragma unroll
        for (int ks = 0; ks < 2; ++ks) {
            const int kc = (ks * 4 + hi) ^ (lrow & 7);
            #pragma unroll
            for (int mi = 0; mi < 4; ++mi)
                af[ks][mi] = *(const bf16x8*)&sA[((wm * 64 + mi * 16 + lrow) * 8 + kc) * 8];
            #pragma unroll
            for (int ni = 0; ni < 4; ++ni)
                bf_[ks][ni] = *(const bf16x8*)&sB[((wn * 64 + ni * 16 + lrow) * 8 + kc) * 8];
        }
        __builtin_amdgcn_s_setprio(1);
        #pragma unroll
        for (int ks = 0; ks < 2; ++ks)
            #pragma unroll
            for (int mi = 0; mi < 4; ++mi)
                #pragma unroll
                for (int ni = 0; ni < 4; ++ni)
                    acc[mi][ni] = __builtin_amdgcn_mfma_f32_16x16x32_bf16(af[ks][mi], bf_[ks][ni], acc[mi][ni], 0, 0, 0);
        __builtin_amdgcn_s_setprio(0);
        __syncthreads();   // all reads done before next overwrite
    }
#undef STAGE

    // epilogue: C/D layout row=hi*4+reg, col=lrow (verified m89)
    if (EPI == 1) {
        #pragma unroll
        for (int mi = 0; mi < 4; ++mi)
            #pragma unroll
            for (int ni = 0; ni < 4; ++ni) {
                int gm0 = row0 + wm * 64 + mi * 16 + hi * 4;
                int gn  = col0 + wn * 64 + ni * 16 + lrow;
                #pragma unroll
                for (int r = 0; r < 4; ++r)
                    ((float*)out0)[(size_t)(gm0 + r) * N + gn] = acc[mi][ni][r];
            }
    } else if (col0 < 1024) {
        // Q: natural [bh][t][d], exp2-domain scale; 32B-run scatter
        const int bb = row0 >> 11;
        #pragma unroll
        for (int mi = 0; mi < 4; ++mi)
            #pragma unroll
            for (int ni = 0; ni < 4; ++ni) {
                int gm0 = row0 + wm * 64 + mi * 16 + hi * 4;
                int gn  = col0 + wn * 64 + ni * 16 + lrow;
                int h = (gn >> 6) & 15, d = gn & 63;
                #pragma unroll
                for (int r = 0; r < 4; ++r) {
                    int t = (gm0 + r) & 2047;
                    ((unsigned short*)out0)[((size_t)(bb * NHEAD + h) * T_DIM + t) * HDIM + d] =
                        f2bf(acc[mi][ni][r] * 0.18033688011112042f);
                }
            }
    } else {
        // K/V: LDS-staged chunk-major -> fully coalesced global writes.
        const bool isK = (col0 < 2048);
        __syncthreads();   // staging LDS dead; safe to reuse
        #pragma unroll
        for (int mi = 0; mi < 4; ++mi) {
            #pragma unroll
            for (int ni = 0; ni < 4; ++ni) {
                const int gnl = wn * 64 + ni * 16 + lrow;   // 0..127 within block
                const int hl = gnl >> 6, d = gnl & 63;
                #pragma unroll
                for (int r = 0; r < 4; ++r) {
                    const int tl = wm * 64 + mi * 16 + hi * 4 + r;   // 0..127
                    int idx;
                    if (isK) idx = (hl * 2 + (tl >> 6)) * 4096 + ((d >> 3) * 64 + (tl & 63)) * 8 + (d & 7);
                    else     idx = (hl * 2 + (tl >> 6)) * 4096 + (((tl >> 3) & 7) * 64 + d) * 8 + (tl & 7);
                    smem[idx] = f2bf(acc[mi][ni][r]);
                }
            }
        }
        __syncthreads();
        unsigned short* outb = (unsigned short*)(isK ? out1 : out2);
        const int bb = row0 >> 11;
        const int h0 = ((col0 - (isK ? 1024 : 2048)) >> 6);   // 2-head aligned
        const int tc0 = (row0 & 2047) >> 6;
        #pragma unroll
        for (int seg = 0; seg < 4; ++seg) {
            const int hl = seg >> 1, tc = seg & 1;
            const size_t gbase = ((size_t)(bb * NHEAD + h0 + hl) * 32 + tc0 + tc) * 4096;
            *(uint4*)(outb + gbase + tid * 8)         = *(const uint4*)(smem + seg * 4096 + tid * 8);
            *(uint4*)(outb + gbase + (tid + 256) * 8) = *(const uint4*)(smem + seg * 4096 + (tid + 256) * 8);
        }
    }
}

// ---------------- causal flash attention: 8 waves x 32 q-rows, swapped 32x32 QK^T ----------------
// 1-D grid of 512 blocks, 512 threads. XCD-affinity mapping (round-robin L%8 = XCD):
//   xcd = L&7, k = L>>3, bh = (k>>3)*8 + xcd, bxx = k<32 ? k&7 : 7-(k&7)
// -> all 8 q-tiles of one bh land on ONE XCD (KV 512KB stays in its L2);
// -> CU pair (k, k+32) gets complementary tile sizes (sum 36) for load balance.
// S^T = mfma_32x32x16(K, Q); P = exp2(S-16) in regs; cvt_pk + permlane32_swap; no P LDS.
__global__ __launch_bounds__(512) void attn_k(
    const unsigned short* __restrict__ qb, const unsigned short* __restrict__ kcm,
    const unsigned short* __restrict__ vcm, unsigned short* __restrict__ yb)
{
    __shared__ __align__(16) unsigned short Ks[2][4096];
    __shared__ __align__(16) unsigned short Vs[2][4096];

    const int tid = threadIdx.x, lane = tid & 63, wave = tid >> 6;
    const int L = (int)blockIdx.x;
    const int k = L >> 3;
    const int bh = ((k >> 3) << 3) + (L & 7);
    const int bxx = (k < 32) ? (k & 7) : 7 - (k & 7);

    const int q32 = lane & 31, hi32 = lane >> 5;
    const unsigned short* Kg = kcm + (size_t)bh * 32 * 4096;
    const unsigned short* Vg = vcm + (size_t)bh * 32 * 4096;

    const int ntiles = 4 * bxx + 4;
    const int q0w = bxx * 256 + wave * 32;
    const int qg = q0w + q32;

    // Q B-fragments direct from global (pre-scaled into exp2 domain)
    const unsigned short* qrow = qb + ((size_t)bh * T_DIM + q0w + q32) * HDIM;
    bf16x8 qf[4];
    #pragma unroll
    for (int kc = 0; kc < 4; ++kc)
        qf[kc] = *(const bf16x8*)(qrow + kc * 16 + hi32 * 8);

    f32x16 o0 = {}, o1 = {};
    float lsum = 0.f;

    gload_lds16(Kg + tid * 8, &Ks[0][tid * 8]);
    gload_lds16(Vg + tid * 8, &Vs[0][tid * 8]);
    __syncthreads();

    int cur = 0;
    for (int jt = 0; jt < ntiles; ++jt) {
        if (jt + 1 < ntiles) {
            gload_lds16(Kg + (size_t)(jt + 1) * 4096 + tid * 8, &Ks[cur ^ 1][tid * 8]);
            gload_lds16(Vg + (size_t)(jt + 1) * 4096 + tid * 8, &Vs[cur ^ 1][tid * 8]);
        }
        if (jt * 64 <= q0w + 31) {   // wave-uniform skip of fully-masked tiles
            // S^T = K · Q  (exp2 domain)
            f32x16 s0 = {}, s1 = {};
            #pragma unroll
            for (int kc = 0; kc < 4; ++kc) {
                bf16x8 a0 = *(const bf16x8*)&Ks[cur][((kc * 2 + hi32) * 64 + q32) * 8];
                bf16x8 a1 = *(const bf16x8*)&Ks[cur][((kc * 2 + hi32) * 64 + 32 + q32) * 8];
                s0 = __builtin_amdgcn_mfma_f32_32x32x16_bf16(a0, qf[kc], s0, 0, 0, 0);
                s1 = __builtin_amdgcn_mfma_f32_32x32x16_bf16(a1, qf[kc], s1, 0, 0, 0);
            }
            // causal mask (diagonal tiles only); kv = jt*64 + blk*32 + crow(r)
            if (jt * 64 + 63 > q0w) {
                #pragma unroll
                for (int r = 0; r < 16; ++r) {
                    int kv0 = jt * 64 + (r & 3) + 8 * (r >> 2) + 4 * hi32;
                    if (kv0 > qg)      s0[r] = -1e30f;
                    if (kv0 + 32 > qg) s1[r] = -1e30f;
                }
            }
            // P = exp2(S-16); pack to bf16; permlane-assemble PV A-frags
            bf16x8 pa[4];
            #pragma unroll
            for (int blk = 0; blk < 2; ++blk) {
                float p_[16]; unsigned w_[8];
                #pragma unroll
                for (int i = 0; i < 16; ++i) {
                    float sv = blk ? s1[i] : s0[i];
                    p_[i] = __builtin_amdgcn_exp2f(sv - 16.0f);
                    lsum += p_[i];
                }
                #pragma unroll
                for (int i = 0; i < 8; ++i) w_[i] = cvtpk_bf16(p_[2 * i], p_[2 * i + 1]);
                pl32swap(w_[0], w_[2]); pl32swap(w_[1], w_[3]);
                pl32swap(w_[4], w_[6]); pl32swap(w_[5], w_[7]);
                pa[blk * 2]     = mk8(w_[0], w_[1], w_[2], w_[3]);
                pa[blk * 2 + 1] = mk8(w_[4], w_[5], w_[6], w_[7]);
            }
            // O += P V
            #pragma unroll
            for (int kvc = 0; kvc < 4; ++kvc) {
                bf16x8 b0 = *(const bf16x8*)&Vs[cur][((kvc * 2 + hi32) * 64 + q32) * 8];
                bf16x8 b1 = *(const bf16x8*)&Vs[cur][((kvc * 2 + hi32) * 64 + 32 + q32) * 8];
                o0 = __builtin_amdgcn_mfma_f32_32x32x16_bf16(pa[kvc], b0, o0, 0, 0, 0);
                o1 = __builtin_amdgcn_mfma_f32_32x32x16_bf16(pa[kvc], b1, o1, 0, 0, 0);
            }
        }
        __syncthreads();   // drains prefetch; next tile ready
        cur ^= 1;
    }

    // l: own-half sum + partner-half via permlane pair
    {
        unsigned la = __float_as_uint(lsum), lb = __float_as_uint(lsum);
        pl32swap(la, lb);
        lsum = __uint_as_float(la) + __uint_as_float(lb);
    }
    // epilogue: y[b*T + t][h*64 + d]; l gathered per output row via shfl
    const int bb2 = bh >> 4, h = bh & 15;
    #pragma unroll
    for (int r = 0; r < 16; ++r) {
        const int cr = (r & 3) + 8 * (r >> 2) + 4 * hi32;
        float inv = 1.0f / __shfl(lsum, cr);
        int t = q0w + cr;
        size_t off = ((size_t)(bb2 * T_DIM + t)) * 1024 + h * HDIM + q32;
        yb[off]      = f2bf(o0[r] * inv);
        yb[off + 32] = f2bf(o1[r] * inv);
    }
}

extern "C" void kernel_launch(void* const* d_in, const int* in_sizes, int n_in,
                              void* d_out, int out_size, void* d_ws, size_t ws_size,
                              hipStream_t stream) {
    const float* x      = (const float*)d_in[0];   // [4,2048,1024]
    const float* w_attn = (const float*)d_in[1];   // [1024,3072]
    const float* w_proj = (const float*)d_in[2];   // [1024,1024]
    float* out = (float*)d_out;                    // [4,2048,1024]

    unsigned short* xb  = (unsigned short*)d_ws;           // [8192][1024]
    unsigned short* wat = xb  + (size_t)8192 * 1024;       // [3072][1024]
    unsigned short* wpt = wat + (size_t)3072 * 1024;       // [1024][1024]
    unsigned short* qb  = wpt + (size_t)1024 * 1024;       // [64][2048][64] natural
    unsigned short* kcm = qb  + (size_t)64 * 2048 * 64;    // [64][32][512][8] chunk-major
    unsigned short* vcm = kcm + (size_t)64 * 2048 * 64;    // [64][32][512][8] chunk-major-T
    unsigned short* yb  = vcm + (size_t)64 * 2048 * 64;    // [8192][1024]

    cvt_bf16_k<<<8192, 256, 0, stream>>>(x, xb, 8192 * 1024);
    transpose_wb_k<<<dim3(96, 32), 256, 0, stream>>>(w_attn, wat, 1024, 3072);
    transpose_wb_k<<<dim3(32, 32), 256, 0, stream>>>(w_proj, wpt, 1024, 1024);

    gemm_bt_k<0><<<dim3(24, 64), 256, 0, stream>>>(xb, wat, qb, kcm, vcm, 8192, 3072, 1024);
    attn_k<<<512, 512, 0, stream>>>(qb, kcm, vcm, yb);
    gemm_bt_k<1><<<dim3(8, 64), 256, 0, stream>>>(yb, wpt, out, nullptr, nullptr, 8192, 1024, 1024);
}